// Round 5
// baseline (1605.553 us; speedup 1.0000x reference)
//
#include <hip/hip_runtime.h>

typedef unsigned short u16;
typedef unsigned int u32;
typedef __attribute__((ext_vector_type(8))) short bf16x8;
typedef __attribute__((ext_vector_type(4))) float f32x4;

__device__ __forceinline__ float bf_lo(u32 u){ return __uint_as_float(u << 16); }
__device__ __forceinline__ float bf_hi(u32 u){ return __uint_as_float(u & 0xffff0000u); }
__device__ __forceinline__ float bf1(u16 u){ return __uint_as_float(((u32)u) << 16); }
__device__ __forceinline__ u16 f2bf(float f){
    u32 u = __float_as_uint(f);
    u32 r = (u + 0x7fffu + ((u >> 16) & 1u)) >> 16;
    return (u16)r;
}
__device__ __forceinline__ u32 pack2(float a, float b){
    return (u32)f2bf(a) | ((u32)f2bf(b) << 16);
}

// ---- per-tensor dtype detection (safety net; expected all-f32) ----
__device__ __forceinline__ bool sane16(u16 v){
    int e = (v >> 7) & 0xff;
    return (v != 0) && e >= 0x70 && e <= 0x85;
}

__global__ __launch_bounds__(64) void detect19_kernel(
    const u16* t0, const u16* t1, const u16* t2, const u16* t3, const u16* t4,
    const u16* t5, const u16* t6, const u16* t7, const u16* t8, const u16* t9,
    const u16* t10, const u16* t11, const u16* t12, const u16* t13, const u16* t14,
    const u16* t15, const u16* t16, const u16* t17, const u16* t18,
    int* __restrict__ flags)
{
    const u16* ptrs[19] = {t0,t1,t2,t3,t4,t5,t6,t7,t8,t9,
                           t10,t11,t12,t13,t14,t15,t16,t17,t18};
    int b = blockIdx.x;
    if (b >= 19){                    // slot 19: internal buffers are bf16
        if (threadIdx.x == 0) flags[19] = 1;
        return;
    }
    u16 v = ptrs[b][threadIdx.x * 2];
    unsigned long long m = __ballot(sane16(v));
    if (threadIdx.x == 0) flags[b] = (__popcll(m) >= 32) ? 1 : 0;
}

__global__ __launch_bounds__(256) void zero_kernel(int* __restrict__ p, int n){
    int i = blockIdx.x * blockDim.x + threadIdx.x;
    if (i < n) p[i] = 0;
}

// -------- MFMA GEMM: C[N,128](bf16) = A[N,128]@W[128,128] (+bias) (+beta*C) --
// Fragment layouts A/B/C verified by r3==r4 cross-check (MFMA vs VALU agree).
__global__ __launch_bounds__(256) void gemm128_kernel(
    const void* __restrict__ A, const void* __restrict__ W,
    const void* __restrict__ bias, u16* __restrict__ C, int N, int beta,
    const int* __restrict__ flags, int af, int wf, int bfi)
{
    const bool a_bf = flags[af] != 0;
    const bool w_bf = flags[wf] != 0;
    int tid = threadIdx.x;
    int wave = tid >> 6, lane = tid & 63;
    int colHalf = wave & 1;
    int ln16 = lane & 15, quad = lane >> 4;

    bf16x8 Bfrag[4][4];
    #pragma unroll
    for (int t = 0; t < 4; ++t){
        int col = colHalf * 64 + t * 16 + ln16;
        #pragma unroll
        for (int q = 0; q < 4; ++q){
            bf16x8 f;
            #pragma unroll
            for (int j = 0; j < 8; ++j){
                int k = q * 32 + quad * 8 + j;
                f[j] = w_bf ? (short)((const u16*)W)[k * 128 + col]
                            : (short)f2bf(((const float*)W)[k * 128 + col]);
            }
            Bfrag[t][q] = f;
        }
    }
    float bv[4];
    #pragma unroll
    for (int t = 0; t < 4; ++t){
        int col = colHalf * 64 + t * 16 + ln16;
        bv[t] = 0.0f;
        if (bias){
            bool b_bf = flags[bfi] != 0;
            bv[t] = b_bf ? bf1(((const u16*)bias)[col]) : ((const float*)bias)[col];
        }
    }

    int rowBlocks = (N + 15) >> 4;
    for (int rb = blockIdx.x * 2 + (wave >> 1); rb < rowBlocks; rb += gridDim.x * 2){
        int row0 = rb * 16;
        int ar = row0 + ln16; if (ar > N - 1) ar = N - 1;   // tail-safe
        bf16x8 Af[4];
        if (a_bf){
            const u16* Arow = (const u16*)A + (size_t)ar * 128 + quad * 8;
            #pragma unroll
            for (int q = 0; q < 4; ++q) Af[q] = *(const bf16x8*)(Arow + q * 32);
        } else {
            const float* Arow = (const float*)A + (size_t)ar * 128 + quad * 8;
            #pragma unroll
            for (int q = 0; q < 4; ++q){
                f32x4 lo = *(const f32x4*)(Arow + q * 32);
                f32x4 hi = *(const f32x4*)(Arow + q * 32 + 4);
                bf16x8 f;
                #pragma unroll
                for (int j = 0; j < 4; ++j){
                    f[j]     = (short)f2bf(lo[j]);
                    f[4 + j] = (short)f2bf(hi[j]);
                }
                Af[q] = f;
            }
        }

        f32x4 acc[4];
        #pragma unroll
        for (int t = 0; t < 4; ++t) acc[t] = (f32x4){0.f, 0.f, 0.f, 0.f};
        #pragma unroll
        for (int q = 0; q < 4; ++q)
            #pragma unroll
            for (int t = 0; t < 4; ++t)
                acc[t] = __builtin_amdgcn_mfma_f32_16x16x32_bf16(Af[q], Bfrag[t][q], acc[t], 0, 0, 0);

        #pragma unroll
        for (int t = 0; t < 4; ++t){
            int col = colHalf * 64 + t * 16 + ln16;
            #pragma unroll
            for (int r = 0; r < 4; ++r){
                int row = row0 + quad * 4 + r;
                if (row < N){
                    u16* p = C + (size_t)row * 128 + col;
                    float v = acc[t][r] + bv[t];
                    if (beta) v += bf1(*p);
                    *p = f2bf(v);
                }
            }
        }
    }
}

// ---------------- CSR build ----------------
__global__ __launch_bounds__(256) void hist_kernel(const int* __restrict__ dst, int E,
                                                   int n_dst, int* __restrict__ cnt){
    int i = blockIdx.x * blockDim.x + threadIdx.x;
    if (i < E){
        int d = dst[i];
        if ((unsigned)d < (unsigned)n_dst) atomicAdd(&cnt[d], 1);
    }
}

__global__ __launch_bounds__(1024) void scan_kernel(const int* __restrict__ cnt, int n,
                                                    int* __restrict__ off, int* __restrict__ cur){
    __shared__ int part[1024];
    int tid = threadIdx.x;
    int per = (n + 1023) >> 10;
    int start = tid * per;
    int end = start + per; if (end > n) end = n;
    int s = 0;
    for (int i = start; i < end; ++i) s += cnt[i];
    part[tid] = s;
    __syncthreads();
    for (int d = 1; d < 1024; d <<= 1){
        int v = (tid >= d) ? part[tid - d] : 0;
        __syncthreads();
        part[tid] += v;
        __syncthreads();
    }
    int run = (tid > 0) ? part[tid - 1] : 0;
    for (int i = start; i < end; ++i){ off[i] = run; cur[i] = run; run += cnt[i]; }
    if (tid == 0) off[n] = part[1023];
}

__global__ __launch_bounds__(256) void fill_kernel(const int* __restrict__ src,
    const int* __restrict__ dst, int E, int n_dst,
    int* __restrict__ cur, int* __restrict__ slot){
    int i = blockIdx.x * blockDim.x + threadIdx.x;
    if (i < E){
        int d = dst[i];
        if ((unsigned)d < (unsigned)n_dst){
            int p = atomicAdd(&cur[d], 1);
            slot[p] = src[i];
        }
    }
}

// ---------------- gather + mean (wave per dst row), internal bf16 ----------------
__global__ __launch_bounds__(256) void gather_kernel(const u16* __restrict__ T,
    const int* __restrict__ off, const int* __restrict__ slot, int n, int n_src,
    u16* __restrict__ aggb){
    int wid = (int)((blockIdx.x * (unsigned)blockDim.x + threadIdx.x) >> 6);
    int lane = threadIdx.x & 63;
    if (wid >= n) return;
    int b = off[wid], e = off[wid + 1];
    float a0 = 0.f, a1 = 0.f;
    for (int j = b; j < e; ++j){
        int s = slot[j];
        if ((unsigned)s >= (unsigned)n_src) s = 0;   // defensive: no OOB read
        u32 u = *(const u32*)(T + (size_t)s * 128 + lane * 2);
        a0 += bf_lo(u); a1 += bf_hi(u);
    }
    int c = e - b; if (c < 1) c = 1;
    float inv = 1.0f / (float)c;
    *(u32*)(aggb + (size_t)wid * 128 + lane * 2) = pack2(a0 * inv, a1 * inv);
}

// ---- row L2-normalize (bf16 S), scale, accumulate into f32 conv (in d_out) ----
__global__ __launch_bounds__(256) void rownorm_kernel(const u16* __restrict__ S,
    float scale, int beta, float* __restrict__ conv, int n){
    int wid = (int)((blockIdx.x * (unsigned)blockDim.x + threadIdx.x) >> 6);
    int lane = threadIdx.x & 63;
    if (wid >= n) return;
    u32 su = *(const u32*)(S + (size_t)wid * 128 + lane * 2);
    float v0 = bf_lo(su), v1 = bf_hi(su);
    float ss = v0 * v0 + v1 * v1;
    #pragma unroll
    for (int m = 1; m < 64; m <<= 1) ss += __shfl_xor(ss, m);
    float s = scale / fmaxf(sqrtf(ss), 1e-12f);
    float2* p = (float2*)(conv + (size_t)wid * 128 + lane * 2);
    float2 o = make_float2(v0 * s, v1 * s);
    if (beta){ float2 u = *p; o.x += u.x; o.y += u.y; }
    *p = o;
}

// ------------- residual + LayerNorm (in-place f32 on conv==out) -------------
__global__ __launch_bounds__(256) void ln_kernel(const u16* __restrict__ T,
    const void* __restrict__ g, const void* __restrict__ be,
    float* __restrict__ out, int n, const int* __restrict__ flags, int gf, int bf){
    int wid = (int)((blockIdx.x * (unsigned)blockDim.x + threadIdx.x) >> 6);
    int lane = threadIdx.x & 63;
    if (wid >= n) return;
    u32 tu = *(const u32*)(T + (size_t)wid * 128 + lane * 2);
    float2* p = (float2*)(out + (size_t)wid * 128 + lane * 2);
    float2 cu = *p;
    float y0 = bf_lo(tu) + cu.x;
    float y1 = bf_hi(tu) + cu.y;
    float s1 = y0 + y1, s2 = y0 * y0 + y1 * y1;
    #pragma unroll
    for (int m = 1; m < 64; m <<= 1){ s1 += __shfl_xor(s1, m); s2 += __shfl_xor(s2, m); }
    float mean = s1 * (1.0f / 128.0f);
    float var = s2 * (1.0f / 128.0f) - mean * mean;
    float rstd = rsqrtf(var + 1e-5f);
    float g0, g1, b0, b1;
    if (flags[gf] != 0){
        u32 gu = ((const u32*)g)[lane];
        g0 = bf_lo(gu); g1 = bf_hi(gu);
    } else {
        float2 gv = ((const float2*)g)[lane];
        g0 = gv.x; g1 = gv.y;
    }
    if (flags[bf] != 0){
        u32 bu = ((const u32*)be)[lane];
        b0 = bf_lo(bu); b1 = bf_hi(bu);
    } else {
        float2 bv = ((const float2*)be)[lane];
        b0 = bv.x; b1 = bv.y;
    }
    *p = make_float2((y0 - mean) * rstd * g0 + b0,
                     (y1 - mean) * rstd * g1 + b1);
}

extern "C" void kernel_launch(void* const* d_in, const int* in_sizes, int n_in,
                              void* d_out, int out_size, void* d_ws, size_t ws_size,
                              hipStream_t stream) {
    const void* xm    = d_in[0];
    const void* xh    = d_in[1];
    const void* Wnt_m = d_in[2];  const void* bnt_m = d_in[3];
    const void* Wnt_h = d_in[4];  const void* bnt_h = d_in[5];
    const void* Wl_mm = d_in[6];  const void* bl_mm = d_in[7];
    const void* Wr_mm = d_in[8];
    const void* Wl_mh = d_in[9];  const void* bl_mh = d_in[10];
    const void* Wr_mh = d_in[11];
    const void* Wl_hm = d_in[12]; const void* bl_hm = d_in[13];
    const void* Wr_hm = d_in[14];
    const void* g_m   = d_in[15]; const void* be_m  = d_in[16];
    const void* g_h   = d_in[17]; const void* be_h  = d_in[18];
    const int* ei_mm = (const int*)d_in[19];
    const int* ei_mh = (const int*)d_in[20];
    const int* ei_hm = (const int*)d_in[21];

    const int D = 128;
    const int NM = in_sizes[0] / D;
    const int NH = in_sizes[1] / D;
    const int E1 = in_sizes[19] / 2;
    const int E2 = in_sizes[20] / 2;
    const int E3 = in_sizes[21] / 2;
    int Emax = E1 > E2 ? E1 : E2; if (E3 > Emax) Emax = E3;
    int Nmax = NM > NH ? NM : NH;

    char* ws = (char*)d_ws;
    size_t woff = 0;
    auto alloc = [&](size_t bytes) -> void* {
        void* p = ws + woff;
        woff += (bytes + 255) & ~(size_t)255;
        return p;
    };
    u16* T_M   = (u16*)alloc((size_t)NM * D * 2);
    u16* T_H   = (u16*)alloc((size_t)NH * D * 2);
    u16* AGGB  = (u16*)alloc((size_t)Nmax * D * 2);
    u16* S     = (u16*)alloc((size_t)Nmax * D * 2);
    int* CNT   = (int*)alloc((size_t)Nmax * 4);
    int* OFF   = (int*)alloc((size_t)(Nmax + 1) * 4);
    int* CUR   = (int*)alloc((size_t)Nmax * 4);
    int* SLOT  = (int*)alloc((size_t)Emax * 4);
    int* FLAGS = (int*)alloc(32 * 4);
    if (woff > ws_size) return;   // diagnostic: zero output -> absmax ~= max|ref|

    float* out    = (float*)d_out;           // OUTPUT IS F32 (r0-r4 taxonomy)
    float* CONV_M = out;                     // d_out doubles as f32 conv accum
    float* CONV_H = out + (size_t)NM * D;

    const int GEMM_GRID = 1563;              // 2 row-blocks/block -> 3126 >= 3125

    detect19_kernel<<<20, 64, 0, stream>>>(
        (const u16*)xm, (const u16*)xh,
        (const u16*)Wnt_m, (const u16*)bnt_m, (const u16*)Wnt_h, (const u16*)bnt_h,
        (const u16*)Wl_mm, (const u16*)bl_mm, (const u16*)Wr_mm,
        (const u16*)Wl_mh, (const u16*)bl_mh, (const u16*)Wr_mh,
        (const u16*)Wl_hm, (const u16*)bl_hm, (const u16*)Wr_hm,
        (const u16*)g_m, (const u16*)be_m, (const u16*)g_h, (const u16*)be_h,
        FLAGS);

    // per-type node transforms: T = X @ W_nt + b_nt  (bf16 out)
    gemm128_kernel<<<GEMM_GRID, 256, 0, stream>>>(xm, Wnt_m, bnt_m, T_M, NM, 0, FLAGS, 0, 2, 3);
    gemm128_kernel<<<GEMM_GRID, 256, 0, stream>>>(xh, Wnt_h, bnt_h, T_H, NH, 0, FLAGS, 1, 4, 5);

    auto do_type = [&](const int* ei, int E, const u16* Tsrc, int n_src,
                       const u16* Tdst, int n_dst,
                       const void* Wl, const void* bl, const void* Wr,
                       int wlF, int blF, int wrF,
                       float* CONV, float scale, int beta){
        int EB = (E + 255) / 256;
        zero_kernel<<<(n_dst + 255) / 256, 256, 0, stream>>>(CNT, n_dst);
        hist_kernel<<<EB, 256, 0, stream>>>(ei + E, E, n_dst, CNT);
        scan_kernel<<<1, 1024, 0, stream>>>(CNT, n_dst, OFF, CUR);
        fill_kernel<<<EB, 256, 0, stream>>>(ei, ei + E, E, n_dst, CUR, SLOT);
        gather_kernel<<<(n_dst + 3) / 4, 256, 0, stream>>>(Tsrc, OFF, SLOT, n_dst, n_src, AGGB);
        gemm128_kernel<<<GEMM_GRID, 256, 0, stream>>>(AGGB, Wl, bl, S, n_dst, 0, FLAGS, 19, wlF, blF);
        gemm128_kernel<<<GEMM_GRID, 256, 0, stream>>>(Tdst, Wr, nullptr, S, n_dst, 1, FLAGS, 19, wrF, 0);
        rownorm_kernel<<<(n_dst + 3) / 4, 256, 0, stream>>>(S, scale, beta, CONV, n_dst);
    };

    // microbe -> microbe (0.5x, init), host -> microbe (0.5x, accumulate)
    do_type(ei_mm, E1, T_M, NM, T_M, NM, Wl_mm, bl_mm, Wr_mm, 6, 7, 8,    CONV_M, 0.5f, 0);
    do_type(ei_hm, E3, T_H, NH, T_M, NM, Wl_hm, bl_hm, Wr_hm, 12, 13, 14, CONV_M, 0.5f, 1);
    // microbe -> host (1.0x, init)
    do_type(ei_mh, E2, T_M, NM, T_H, NH, Wl_mh, bl_mh, Wr_mh, 9, 10, 11,  CONV_H, 1.0f, 0);

    // residual + LayerNorm, in place on f32 d_out
    ln_kernel<<<(NM + 3) / 4, 256, 0, stream>>>(T_M, g_m, be_m, CONV_M, NM, FLAGS, 15, 16);
    ln_kernel<<<(NH + 3) / 4, 256, 0, stream>>>(T_H, g_h, be_h, CONV_H, NH, FLAGS, 17, 18);
}

// Round 6
// 678.219 us; speedup vs baseline: 2.3673x; 2.3673x over previous
//
#include <hip/hip_runtime.h>

typedef unsigned short u16;
typedef unsigned int u32;
typedef __attribute__((ext_vector_type(8))) short bf16x8;
typedef __attribute__((ext_vector_type(4))) float f32x4;

__device__ __forceinline__ float bf_lo(u32 u){ return __uint_as_float(u << 16); }
__device__ __forceinline__ float bf_hi(u32 u){ return __uint_as_float(u & 0xffff0000u); }
__device__ __forceinline__ float bf1(u16 u){ return __uint_as_float(((u32)u) << 16); }
__device__ __forceinline__ u16 f2bf(float f){
    u32 u = __float_as_uint(f);
    u32 r = (u + 0x7fffu + ((u >> 16) & 1u)) >> 16;
    return (u16)r;
}
__device__ __forceinline__ u32 pack2(float a, float b){
    return (u32)f2bf(a) | ((u32)f2bf(b) << 16);
}

__global__ __launch_bounds__(256) void zero_kernel(int* __restrict__ p, int n){
    int i = blockIdx.x * blockDim.x + threadIdx.x;
    if (i < n) p[i] = 0;
}

// ---- node-transform GEMM: T[N,128](bf16) = X[N,128](f32) @ W(f32) + b(f32) --
// 4 waves/block: wave&1 -> column half, wave>>1 -> row-tile parity.
__global__ __launch_bounds__(256) void ntgemm_kernel(
    const float* __restrict__ A, const float* __restrict__ W,
    const float* __restrict__ bias, u16* __restrict__ C, int N)
{
    int tid = threadIdx.x;
    int wave = tid >> 6, lane = tid & 63;
    int colHalf = wave & 1;
    int ln16 = lane & 15, quad = lane >> 4;

    bf16x8 Bfrag[4][4];
    #pragma unroll
    for (int t = 0; t < 4; ++t){
        int col = colHalf * 64 + t * 16 + ln16;
        #pragma unroll
        for (int q = 0; q < 4; ++q){
            bf16x8 f;
            #pragma unroll
            for (int j = 0; j < 8; ++j)
                f[j] = (short)f2bf(W[(q * 32 + quad * 8 + j) * 128 + col]);
            Bfrag[t][q] = f;
        }
    }
    float bv[4];
    #pragma unroll
    for (int t = 0; t < 4; ++t)
        bv[t] = bias[colHalf * 64 + t * 16 + ln16];

    int rowBlocks = (N + 15) >> 4;
    for (int rb = blockIdx.x * 2 + (wave >> 1); rb < rowBlocks; rb += gridDim.x * 2){
        int row0 = rb * 16;
        int ar = row0 + ln16; if (ar > N - 1) ar = N - 1;
        const float* Arow = A + (size_t)ar * 128 + quad * 8;
        bf16x8 Af[4];
        #pragma unroll
        for (int q = 0; q < 4; ++q){
            f32x4 lo = *(const f32x4*)(Arow + q * 32);
            f32x4 hi = *(const f32x4*)(Arow + q * 32 + 4);
            bf16x8 f;
            #pragma unroll
            for (int j = 0; j < 4; ++j){ f[j] = (short)f2bf(lo[j]); f[4+j] = (short)f2bf(hi[j]); }
            Af[q] = f;
        }

        f32x4 acc[4];
        #pragma unroll
        for (int t = 0; t < 4; ++t) acc[t] = (f32x4){bv[t], bv[t], bv[t], bv[t]};
        #pragma unroll
        for (int q = 0; q < 4; ++q)
            #pragma unroll
            for (int t = 0; t < 4; ++t)
                acc[t] = __builtin_amdgcn_mfma_f32_16x16x32_bf16(Af[q], Bfrag[t][q], acc[t], 0, 0, 0);

        #pragma unroll
        for (int t = 0; t < 4; ++t){
            int col = colHalf * 64 + t * 16 + ln16;
            #pragma unroll
            for (int r = 0; r < 4; ++r){
                int row = row0 + quad * 4 + r;
                if (row < N) C[(size_t)row * 128 + col] = f2bf(acc[t][r]);
            }
        }
    }
}

// ---------------- batched CSR build over 3 edge types ----------------
__global__ __launch_bounds__(256) void hist3_kernel(
    const int* __restrict__ d0, const int* __restrict__ d1, const int* __restrict__ d2,
    int E0, int E1, int E2, int b0, int b1, int b2, int n0, int n1, int n2,
    int* __restrict__ cnt)
{
    int t = blockIdx.y;
    int i = blockIdx.x * 256 + threadIdx.x;
    const int* d = t == 0 ? d0 : (t == 1 ? d1 : d2);
    int E = t == 0 ? E0 : (t == 1 ? E1 : E2);
    int b = t == 0 ? b0 : (t == 1 ? b1 : b2);
    int n = t == 0 ? n0 : (t == 1 ? n1 : n2);
    if (i < E){
        int x = d[i];
        if ((unsigned)x < (unsigned)n) atomicAdd(&cnt[b + x], 1);
    }
}

// 3-phase device-wide exclusive scan (n up to 74*2048)
__global__ __launch_bounds__(256) void scan_blocks_kernel(
    const int* __restrict__ cnt, int n, int* __restrict__ off, int* __restrict__ part)
{
    __shared__ int lds[256];
    int tid = threadIdx.x;
    int base = blockIdx.x * 2048 + tid * 8;
    int v[8]; int s = 0;
    #pragma unroll
    for (int j = 0; j < 8; ++j){
        int idx = base + j;
        int c = (idx < n) ? cnt[idx] : 0;
        v[j] = s; s += c;
    }
    lds[tid] = s;
    __syncthreads();
    for (int d = 1; d < 256; d <<= 1){
        int t = (tid >= d) ? lds[tid - d] : 0;
        __syncthreads();
        lds[tid] += t;
        __syncthreads();
    }
    int thrBase = (tid > 0) ? lds[tid - 1] : 0;
    if (tid == 255) part[blockIdx.x] = lds[255];
    #pragma unroll
    for (int j = 0; j < 8; ++j){
        int idx = base + j;
        if (idx < n) off[idx] = thrBase + v[j];
    }
}

__global__ __launch_bounds__(128) void scan_part_kernel(
    int* __restrict__ part, int np, int* __restrict__ total_slot)
{
    __shared__ int lds[128];
    int tid = threadIdx.x;
    lds[tid] = (tid < np) ? part[tid] : 0;
    __syncthreads();
    for (int d = 1; d < 128; d <<= 1){
        int t = (tid >= d) ? lds[tid - d] : 0;
        __syncthreads();
        lds[tid] += t;
        __syncthreads();
    }
    if (tid < np) part[tid] = (tid > 0) ? lds[tid - 1] : 0;
    if (tid == 0) *total_slot = lds[np - 1 < 0 ? 0 : np - 1];
}

__global__ __launch_bounds__(256) void scan_add_kernel(
    int* __restrict__ off, int* __restrict__ cur, const int* __restrict__ part, int n)
{
    int i = blockIdx.x * 256 + threadIdx.x;
    if (i < n){
        int v = off[i] + part[i >> 11];
        off[i] = v;
        cur[i] = v;
    }
}

__global__ __launch_bounds__(256) void fill3_kernel(
    const int* __restrict__ s0, const int* __restrict__ s1, const int* __restrict__ s2,
    const int* __restrict__ d0, const int* __restrict__ d1, const int* __restrict__ d2,
    int E0, int E1, int E2, int b0, int b1, int b2, int n0, int n1, int n2,
    int* __restrict__ cur, int* __restrict__ slot)
{
    int t = blockIdx.y;
    int i = blockIdx.x * 256 + threadIdx.x;
    const int* sp = t == 0 ? s0 : (t == 1 ? s1 : s2);
    const int* dp = t == 0 ? d0 : (t == 1 ? d1 : d2);
    int E = t == 0 ? E0 : (t == 1 ? E1 : E2);
    int b = t == 0 ? b0 : (t == 1 ? b1 : b2);
    int n = t == 0 ? n0 : (t == 1 ? n1 : n2);
    if (i < E){
        int x = dp[i];
        if ((unsigned)x < (unsigned)n){
            int p = atomicAdd(&cur[b + x], 1);
            slot[p] = sp[i];
        }
    }
}

// ---------------- gather + mean (wave per dst row), bf16 ----------------
__global__ __launch_bounds__(256) void gather_kernel(const u16* __restrict__ T,
    const int* __restrict__ off, const int* __restrict__ slot, int n, int n_src,
    u16* __restrict__ aggb){
    int wid = (int)((blockIdx.x * (unsigned)blockDim.x + threadIdx.x) >> 6);
    int lane = threadIdx.x & 63;
    if (wid >= n) return;
    int b = off[wid], e = off[wid + 1];
    float a0 = 0.f, a1 = 0.f;
    for (int j = b; j < e; ++j){
        int s = slot[j];
        if ((unsigned)s >= (unsigned)n_src) s = 0;
        u32 u = *(const u32*)(T + (size_t)s * 128 + lane * 2);
        a0 += bf_lo(u); a1 += bf_hi(u);
    }
    int c = e - b; if (c < 1) c = 1;
    float inv = 1.0f / (float)c;
    *(u32*)(aggb + (size_t)wid * 128 + lane * 2) = pack2(a0 * inv, a1 * inv);
}

// ---- fused SAGE: S = agg@Wl + bl + tdst@Wr; row-L2-norm; conv += scale*S ----
// 4 waves/block, wave = column quarter (32 cols). One 16-row tile per iter.
// Cross-wave row sum-of-squares via LDS.
__global__ __launch_bounds__(256) void sage_kernel(
    const u16* __restrict__ Aagg, const u16* __restrict__ Tdst,
    const float* __restrict__ Wl, const float* __restrict__ bl,
    const float* __restrict__ Wr, float* __restrict__ conv,
    int N, float scale, int beta)
{
    __shared__ float ssLDS[4][16];
    int tid = threadIdx.x;
    int wave = tid >> 6, lane = tid & 63;
    int ln16 = lane & 15, quad = lane >> 4;

    // B fragments for both weights, this wave's 32 columns (t=0,1)
    bf16x8 BL[2][4], BR[2][4];
    #pragma unroll
    for (int t = 0; t < 2; ++t){
        int col = wave * 32 + t * 16 + ln16;
        #pragma unroll
        for (int q = 0; q < 4; ++q){
            bf16x8 fl, fr;
            #pragma unroll
            for (int j = 0; j < 8; ++j){
                int k = q * 32 + quad * 8 + j;
                fl[j] = (short)f2bf(Wl[k * 128 + col]);
                fr[j] = (short)f2bf(Wr[k * 128 + col]);
            }
            BL[t][q] = fl; BR[t][q] = fr;
        }
    }
    float bv[2];
    #pragma unroll
    for (int t = 0; t < 2; ++t) bv[t] = bl[wave * 32 + t * 16 + ln16];

    int tiles = (N + 15) >> 4;
    for (int tile = blockIdx.x; tile < tiles; tile += gridDim.x){
        int row0 = tile * 16;
        int ar = row0 + ln16; if (ar > N - 1) ar = N - 1;
        const u16* Ar1 = Aagg + (size_t)ar * 128 + quad * 8;
        const u16* Ar2 = Tdst + (size_t)ar * 128 + quad * 8;
        bf16x8 AfL[4], AfR[4];
        #pragma unroll
        for (int q = 0; q < 4; ++q){
            AfL[q] = *(const bf16x8*)(Ar1 + q * 32);
            AfR[q] = *(const bf16x8*)(Ar2 + q * 32);
        }

        f32x4 acc[2];
        #pragma unroll
        for (int t = 0; t < 2; ++t) acc[t] = (f32x4){bv[t], bv[t], bv[t], bv[t]};
        #pragma unroll
        for (int q = 0; q < 4; ++q)
            #pragma unroll
            for (int t = 0; t < 2; ++t)
                acc[t] = __builtin_amdgcn_mfma_f32_16x16x32_bf16(AfL[q], BL[t][q], acc[t], 0, 0, 0);
        #pragma unroll
        for (int q = 0; q < 4; ++q)
            #pragma unroll
            for (int t = 0; t < 2; ++t)
                acc[t] = __builtin_amdgcn_mfma_f32_16x16x32_bf16(AfR[q], BR[t][q], acc[t], 0, 0, 0);

        // per-row sum of squares over this wave's 32 cols
        float ssr[4];
        #pragma unroll
        for (int r = 0; r < 4; ++r){
            float s = acc[0][r] * acc[0][r] + acc[1][r] * acc[1][r];
            #pragma unroll
            for (int m = 1; m < 16; m <<= 1) s += __shfl_xor(s, m);
            ssr[r] = s;
        }
        if (ln16 == 0){
            #pragma unroll
            for (int r = 0; r < 4; ++r) ssLDS[wave][quad * 4 + r] = ssr[r];
        }
        __syncthreads();

        #pragma unroll
        for (int r = 0; r < 4; ++r){
            int row = row0 + quad * 4 + r;
            if (row >= N) continue;
            int r16 = quad * 4 + r;
            float tot = ssLDS[0][r16] + ssLDS[1][r16] + ssLDS[2][r16] + ssLDS[3][r16];
            float s = scale / fmaxf(sqrtf(tot), 1e-12f);
            #pragma unroll
            for (int t = 0; t < 2; ++t){
                int col = wave * 32 + t * 16 + ln16;
                float* p = conv + (size_t)row * 128 + col;
                float v = acc[t][r] * s;
                if (beta) v += *p;
                *p = v;
            }
        }
        __syncthreads();   // protect ssLDS before next tile
    }
}

// ------------- residual + LayerNorm (in-place f32 on conv==out) -------------
__global__ __launch_bounds__(256) void ln_kernel(const u16* __restrict__ T,
    const float* __restrict__ g, const float* __restrict__ be,
    float* __restrict__ out, int n){
    int wid = (int)((blockIdx.x * (unsigned)blockDim.x + threadIdx.x) >> 6);
    int lane = threadIdx.x & 63;
    if (wid >= n) return;
    u32 tu = *(const u32*)(T + (size_t)wid * 128 + lane * 2);
    float2* p = (float2*)(out + (size_t)wid * 128 + lane * 2);
    float2 cu = *p;
    float y0 = bf_lo(tu) + cu.x;
    float y1 = bf_hi(tu) + cu.y;
    float s1 = y0 + y1, s2 = y0 * y0 + y1 * y1;
    #pragma unroll
    for (int m = 1; m < 64; m <<= 1){ s1 += __shfl_xor(s1, m); s2 += __shfl_xor(s2, m); }
    float mean = s1 * (1.0f / 128.0f);
    float var = s2 * (1.0f / 128.0f) - mean * mean;
    float rstd = rsqrtf(var + 1e-5f);
    float2 gv = ((const float2*)g)[lane];
    float2 bv = ((const float2*)be)[lane];
    *p = make_float2((y0 - mean) * rstd * gv.x + bv.x,
                     (y1 - mean) * rstd * gv.y + bv.y);
}

extern "C" void kernel_launch(void* const* d_in, const int* in_sizes, int n_in,
                              void* d_out, int out_size, void* d_ws, size_t ws_size,
                              hipStream_t stream) {
    const float* xm    = (const float*)d_in[0];
    const float* xh    = (const float*)d_in[1];
    const float* Wnt_m = (const float*)d_in[2];  const float* bnt_m = (const float*)d_in[3];
    const float* Wnt_h = (const float*)d_in[4];  const float* bnt_h = (const float*)d_in[5];
    const float* Wl_mm = (const float*)d_in[6];  const float* bl_mm = (const float*)d_in[7];
    const float* Wr_mm = (const float*)d_in[8];
    const float* Wl_mh = (const float*)d_in[9];  const float* bl_mh = (const float*)d_in[10];
    const float* Wr_mh = (const float*)d_in[11];
    const float* Wl_hm = (const float*)d_in[12]; const float* bl_hm = (const float*)d_in[13];
    const float* Wr_hm = (const float*)d_in[14];
    const float* g_m   = (const float*)d_in[15]; const float* be_m  = (const float*)d_in[16];
    const float* g_h   = (const float*)d_in[17]; const float* be_h  = (const float*)d_in[18];
    const int* ei_mm = (const int*)d_in[19];
    const int* ei_mh = (const int*)d_in[20];
    const int* ei_hm = (const int*)d_in[21];

    const int D = 128;
    const int NM = in_sizes[0] / D;
    const int NH = in_sizes[1] / D;
    const int E1 = in_sizes[19] / 2;   // mm
    const int E2 = in_sizes[20] / 2;   // mh
    const int E3 = in_sizes[21] / 2;   // hm
    const int Esum = E1 + E2 + E3;
    const int n3 = 2 * NM + NH;        // type0: mm->M, type1: hm->M, type2: mh->H

    char* ws = (char*)d_ws;
    size_t woff = 0;
    auto alloc = [&](size_t bytes) -> void* {
        void* p = ws + woff;
        woff += (bytes + 255) & ~(size_t)255;
        return p;
    };
    u16* T_M   = (u16*)alloc((size_t)NM * D * 2);
    u16* T_H   = (u16*)alloc((size_t)NH * D * 2);
    u16* AGGB  = (u16*)alloc((size_t)(NM > NH ? NM : NH) * D * 2);
    int* CNT3  = (int*)alloc((size_t)n3 * 4);
    int* OFF3  = (int*)alloc((size_t)(n3 + 1) * 4);
    int* CUR3  = (int*)alloc((size_t)n3 * 4);
    int* SLOT3 = (int*)alloc((size_t)Esum * 4);
    int* PART  = (int*)alloc(1024 * 4);
    if (woff > ws_size) return;   // diagnostic: zero output -> absmax ~= max|ref|

    float* out    = (float*)d_out;
    float* CONV_M = out;
    float* CONV_H = out + (size_t)NM * D;

    const int b0 = 0, b1 = NM, b2 = 2 * NM;
    int Emax = E1 > E2 ? E1 : E2; if (E3 > Emax) Emax = E3;
    const dim3 egrid((Emax + 255) / 256, 3);
    const int scanBlocks = (n3 + 2047) / 2048;

    // ---- batched CSR build (types: 0=mm dst M, 1=hm dst M, 2=mh dst H) ----
    zero_kernel<<<(n3 + 255) / 256, 256, 0, stream>>>(CNT3, n3);
    hist3_kernel<<<egrid, 256, 0, stream>>>(
        ei_mm + E1, ei_hm + E3, ei_mh + E2,
        E1, E3, E2, b0, b1, b2, NM, NM, NH, CNT3);
    scan_blocks_kernel<<<scanBlocks, 256, 0, stream>>>(CNT3, n3, OFF3, PART);
    scan_part_kernel<<<1, 128, 0, stream>>>(PART, scanBlocks, OFF3 + n3);
    scan_add_kernel<<<(n3 + 255) / 256, 256, 0, stream>>>(OFF3, CUR3, PART, n3);
    fill3_kernel<<<egrid, 256, 0, stream>>>(
        ei_mm, ei_hm, ei_mh,
        ei_mm + E1, ei_hm + E3, ei_mh + E2,
        E1, E3, E2, b0, b1, b2, NM, NM, NH, CUR3, SLOT3);

    // ---- node transforms ----
    ntgemm_kernel<<<1563, 256, 0, stream>>>(xm, Wnt_m, bnt_m, T_M, NM);
    ntgemm_kernel<<<1563, 256, 0, stream>>>(xh, Wnt_h, bnt_h, T_H, NH);

    // ---- per edge type: gather + fused SAGE (gemm x2 + rownorm + conv accum) --
    // type0: mm (src T_M, dst M), scale 0.5, init
    gather_kernel<<<(NM + 3) / 4, 256, 0, stream>>>(T_M, OFF3 + b0, SLOT3, NM, NM, AGGB);
    sage_kernel<<<1563, 256, 0, stream>>>(AGGB, T_M, Wl_mm, bl_mm, Wr_mm, CONV_M, NM, 0.5f, 0);
    // type1: hm (src T_H, dst M), scale 0.5, accumulate
    gather_kernel<<<(NM + 3) / 4, 256, 0, stream>>>(T_H, OFF3 + b1, SLOT3, NM, NH, AGGB);
    sage_kernel<<<1563, 256, 0, stream>>>(AGGB, T_M, Wl_hm, bl_hm, Wr_hm, CONV_M, NM, 0.5f, 1);
    // type2: mh (src T_M, dst H), scale 1.0, init
    gather_kernel<<<(NH + 3) / 4, 256, 0, stream>>>(T_M, OFF3 + b2, SLOT3, NH, NM, AGGB);
    sage_kernel<<<1563, 256, 0, stream>>>(AGGB, T_H, Wl_mh, bl_mh, Wr_mh, CONV_H, NH, 1.0f, 0);

    // ---- residual + LayerNorm, in place on f32 d_out ----
    ln_kernel<<<(NM + 3) / 4, 256, 0, stream>>>(T_M, g_m, be_m, CONV_M, NM);
    ln_kernel<<<(NH + 3) / 4, 256, 0, stream>>>(T_H, g_h, be_h, CONV_H, NH);
}

// Round 7
// 668.595 us; speedup vs baseline: 2.4014x; 1.0144x over previous
//
#include <hip/hip_runtime.h>

typedef unsigned short u16;
typedef unsigned int u32;
typedef __attribute__((ext_vector_type(8))) short bf16x8;
typedef __attribute__((ext_vector_type(4))) float f32x4;

__device__ __forceinline__ float bf_lo(u32 u){ return __uint_as_float(u << 16); }
__device__ __forceinline__ float bf_hi(u32 u){ return __uint_as_float(u & 0xffff0000u); }
__device__ __forceinline__ u16 f2bf(float f){
    u32 u = __float_as_uint(f);
    u32 r = (u + 0x7fffu + ((u >> 16) & 1u)) >> 16;
    return (u16)r;
}
__device__ __forceinline__ u32 pack2(float a, float b){
    return (u32)f2bf(a) | ((u32)f2bf(b) << 16);
}

// ======== fused: hist3 (atomic histogram) || ntgemm_M || ntgemm_H ========
// blockIdx partition: [0,HB) hist, [HB,HB+gm) ntgemm M, [HB+gm,HB+gm+gh) ntgemm H.
__global__ __launch_bounds__(256) void fusedA_kernel(
    const int* __restrict__ d0, const int* __restrict__ d1, const int* __restrict__ d2,
    int E0, int E1, int E2, int b0, int b1, int b2, int n0, int n1, int n2,
    int* __restrict__ cnt, int h0, int h1, int h2,
    const float* __restrict__ Xm, const float* __restrict__ Wm,
    const float* __restrict__ bm, u16* __restrict__ Tm, int NM,
    const float* __restrict__ Xh, const float* __restrict__ Wh,
    const float* __restrict__ bh, u16* __restrict__ Th, int NH,
    int gm, int gh)
{
    int bid = blockIdx.x;
    int HB = h0 + h1 + h2;
    if (bid < HB){
        int t, lb;
        if (bid < h0){ t = 0; lb = bid; }
        else if (bid < h0 + h1){ t = 1; lb = bid - h0; }
        else { t = 2; lb = bid - h0 - h1; }
        const int* d = t == 0 ? d0 : (t == 1 ? d1 : d2);
        int E = t == 0 ? E0 : (t == 1 ? E1 : E2);
        int b = t == 0 ? b0 : (t == 1 ? b1 : b2);
        int n = t == 0 ? n0 : (t == 1 ? n1 : n2);
        int i = lb * 256 + threadIdx.x;
        if (i < E){
            int x = d[i];
            if ((unsigned)x < (unsigned)n) atomicAdd(&cnt[b + x], 1);
        }
        return;
    }
    bid -= HB;
    const float *A, *W, *bias; u16* C; int N, lgrid, lbid;
    if (bid < gm){ A = Xm; W = Wm; bias = bm; C = Tm; N = NM; lgrid = gm; lbid = bid; }
    else         { A = Xh; W = Wh; bias = bh; C = Th; N = NH; lgrid = gh; lbid = bid - gm; }

    int tid = threadIdx.x;
    int wave = tid >> 6, lane = tid & 63;
    int colHalf = wave & 1;
    int ln16 = lane & 15, quad = lane >> 4;

    bf16x8 Bfrag[4][4];
    #pragma unroll
    for (int t = 0; t < 4; ++t){
        int col = colHalf * 64 + t * 16 + ln16;
        #pragma unroll
        for (int q = 0; q < 4; ++q){
            bf16x8 f;
            #pragma unroll
            for (int j = 0; j < 8; ++j)
                f[j] = (short)f2bf(W[(q * 32 + quad * 8 + j) * 128 + col]);
            Bfrag[t][q] = f;
        }
    }
    float bv[4];
    #pragma unroll
    for (int t = 0; t < 4; ++t)
        bv[t] = bias[colHalf * 64 + t * 16 + ln16];

    int rowBlocks = (N + 15) >> 4;
    for (int rb = lbid * 2 + (wave >> 1); rb < rowBlocks; rb += lgrid * 2){
        int row0 = rb * 16;
        int ar = row0 + ln16; if (ar > N - 1) ar = N - 1;
        const float* Arow = A + (size_t)ar * 128 + quad * 8;
        bf16x8 Af[4];
        #pragma unroll
        for (int q = 0; q < 4; ++q){
            f32x4 lo = *(const f32x4*)(Arow + q * 32);
            f32x4 hi = *(const f32x4*)(Arow + q * 32 + 4);
            bf16x8 f;
            #pragma unroll
            for (int j = 0; j < 4; ++j){ f[j] = (short)f2bf(lo[j]); f[4+j] = (short)f2bf(hi[j]); }
            Af[q] = f;
        }
        f32x4 acc[4];
        #pragma unroll
        for (int t = 0; t < 4; ++t) acc[t] = (f32x4){bv[t], bv[t], bv[t], bv[t]};
        #pragma unroll
        for (int q = 0; q < 4; ++q)
            #pragma unroll
            for (int t = 0; t < 4; ++t)
                acc[t] = __builtin_amdgcn_mfma_f32_16x16x32_bf16(Af[q], Bfrag[t][q], acc[t], 0, 0, 0);
        #pragma unroll
        for (int t = 0; t < 4; ++t){
            int col = colHalf * 64 + t * 16 + ln16;
            #pragma unroll
            for (int r = 0; r < 4; ++r){
                int row = row0 + quad * 4 + r;
                if (row < N) C[(size_t)row * 128 + col] = f2bf(acc[t][r]);
            }
        }
    }
}

// ---------------- 3-phase device-wide exclusive scan ----------------
__global__ __launch_bounds__(256) void scan_blocks_kernel(
    const int* __restrict__ cnt, int n, int* __restrict__ off, int* __restrict__ part)
{
    __shared__ int lds[256];
    int tid = threadIdx.x;
    int base = blockIdx.x * 2048 + tid * 8;
    int v[8]; int s = 0;
    #pragma unroll
    for (int j = 0; j < 8; ++j){
        int idx = base + j;
        int c = (idx < n) ? cnt[idx] : 0;
        v[j] = s; s += c;
    }
    lds[tid] = s;
    __syncthreads();
    for (int d = 1; d < 256; d <<= 1){
        int t = (tid >= d) ? lds[tid - d] : 0;
        __syncthreads();
        lds[tid] += t;
        __syncthreads();
    }
    int thrBase = (tid > 0) ? lds[tid - 1] : 0;
    if (tid == 255) part[blockIdx.x] = lds[255];
    #pragma unroll
    for (int j = 0; j < 8; ++j){
        int idx = base + j;
        if (idx < n) off[idx] = thrBase + v[j];
    }
}

__global__ __launch_bounds__(128) void scan_part_kernel(
    int* __restrict__ part, int np, int* __restrict__ total_slot)
{
    __shared__ int lds[128];
    int tid = threadIdx.x;
    lds[tid] = (tid < np) ? part[tid] : 0;
    __syncthreads();
    for (int d = 1; d < 128; d <<= 1){
        int t = (tid >= d) ? lds[tid - d] : 0;
        __syncthreads();
        lds[tid] += t;
        __syncthreads();
    }
    if (tid < np) part[tid] = (tid > 0) ? lds[tid - 1] : 0;
    if (tid == 0) *total_slot = lds[np - 1 < 0 ? 0 : np - 1];
}

__global__ __launch_bounds__(256) void scan_add_kernel(
    int* __restrict__ off, int* __restrict__ cur, const int* __restrict__ part, int n)
{
    int i = blockIdx.x * 256 + threadIdx.x;
    if (i < n){
        int v = off[i] + part[i >> 11];
        off[i] = v;
        cur[i] = v;
    }
}

__global__ __launch_bounds__(256) void fill3_kernel(
    const int* __restrict__ s0, const int* __restrict__ s1, const int* __restrict__ s2,
    const int* __restrict__ d0, const int* __restrict__ d1, const int* __restrict__ d2,
    int E0, int E1, int E2, int b0, int b1, int b2, int n0, int n1, int n2,
    int* __restrict__ cur, int* __restrict__ slot)
{
    int t = blockIdx.y;
    int i = blockIdx.x * 256 + threadIdx.x;
    const int* sp = t == 0 ? s0 : (t == 1 ? s1 : s2);
    const int* dp = t == 0 ? d0 : (t == 1 ? d1 : d2);
    int E = t == 0 ? E0 : (t == 1 ? E1 : E2);
    int b = t == 0 ? b0 : (t == 1 ? b1 : b2);
    int n = t == 0 ? n0 : (t == 1 ? n1 : n2);
    if (i < E){
        int x = dp[i];
        if ((unsigned)x < (unsigned)n){
            int p = atomicAdd(&cur[b + x], 1);
            slot[p] = sp[i];
        }
    }
}

// ===== fused gather + SAGE: mean(T_src[nbrs]) -> LDS -> MFMA x2 -> L2norm ->
//       conv (+=) scale * normalized  =====
// 4 waves/block; 16 dst rows per tile. Wave w gathers rows 4w..4w+3, then is
// column-quarter w for the GEMM phase. aggLDS row stride 68 u32 (16B-aligned,
// bank-rotated: only free 2-way conflicts on ds_read_b128).
__global__ __launch_bounds__(256) void sage_g_kernel(
    const u16* __restrict__ Tsrc, const u16* __restrict__ Tdst,
    const int* __restrict__ off, const int* __restrict__ slot, int n_src,
    const float* __restrict__ Wl, const float* __restrict__ bl,
    const float* __restrict__ Wr, float* __restrict__ conv,
    int N, float scale, int beta)
{
    __shared__ u32 aggLDS[16 * 68];
    __shared__ float ssLDS[4][16];
    int tid = threadIdx.x;
    int wave = tid >> 6, lane = tid & 63;
    int ln16 = lane & 15, quad = lane >> 4;

    // B fragments for both weights (this wave's 32 columns)
    bf16x8 BL[2][4], BR[2][4];
    #pragma unroll
    for (int t = 0; t < 2; ++t){
        int col = wave * 32 + t * 16 + ln16;
        #pragma unroll
        for (int q = 0; q < 4; ++q){
            bf16x8 fl, fr;
            #pragma unroll
            for (int j = 0; j < 8; ++j){
                int k = q * 32 + quad * 8 + j;
                fl[j] = (short)f2bf(Wl[k * 128 + col]);
                fr[j] = (short)f2bf(Wr[k * 128 + col]);
            }
            BL[t][q] = fl; BR[t][q] = fr;
        }
    }
    float bv[2];
    #pragma unroll
    for (int t = 0; t < 2; ++t) bv[t] = bl[wave * 32 + t * 16 + ln16];

    int tiles = (N + 15) >> 4;
    for (int tile = blockIdx.x; tile < tiles; tile += gridDim.x){
        int row0 = tile * 16;

        // ---- phase 1: gather means for rows 4*wave .. 4*wave+3 ----
        #pragma unroll
        for (int r = 0; r < 4; ++r){
            int lrow = wave * 4 + r;
            int g = row0 + lrow;
            float p0 = 0.f, p1 = 0.f, q0 = 0.f, q1 = 0.f;
            float r0 = 0.f, r1 = 0.f, s0 = 0.f, s1 = 0.f;
            int cnt = 0;
            if (g < N){
                int b = off[g], e = off[g + 1];
                cnt = e - b;
                int j = b;
                for (; j + 4 <= e; j += 4){
                    int i0 = slot[j], i1 = slot[j+1], i2 = slot[j+2], i3 = slot[j+3];
                    if ((unsigned)i0 >= (unsigned)n_src) i0 = 0;
                    if ((unsigned)i1 >= (unsigned)n_src) i1 = 0;
                    if ((unsigned)i2 >= (unsigned)n_src) i2 = 0;
                    if ((unsigned)i3 >= (unsigned)n_src) i3 = 0;
                    u32 u0 = *(const u32*)(Tsrc + (size_t)i0 * 128 + lane * 2);
                    u32 u1 = *(const u32*)(Tsrc + (size_t)i1 * 128 + lane * 2);
                    u32 u2 = *(const u32*)(Tsrc + (size_t)i2 * 128 + lane * 2);
                    u32 u3 = *(const u32*)(Tsrc + (size_t)i3 * 128 + lane * 2);
                    p0 += bf_lo(u0); p1 += bf_hi(u0);
                    q0 += bf_lo(u1); q1 += bf_hi(u1);
                    r0 += bf_lo(u2); r1 += bf_hi(u2);
                    s0 += bf_lo(u3); s1 += bf_hi(u3);
                }
                for (; j < e; ++j){
                    int i0 = slot[j];
                    if ((unsigned)i0 >= (unsigned)n_src) i0 = 0;
                    u32 u0 = *(const u32*)(Tsrc + (size_t)i0 * 128 + lane * 2);
                    p0 += bf_lo(u0); p1 += bf_hi(u0);
                }
            }
            float a0 = (p0 + q0) + (r0 + s0);
            float a1 = (p1 + q1) + (r1 + s1);
            int c = cnt < 1 ? 1 : cnt;
            float inv = 1.0f / (float)c;
            aggLDS[lrow * 68 + lane] = pack2(a0 * inv, a1 * inv);
        }
        __syncthreads();

        // ---- phase 2: two MFMA GEMM halves on [agg | Tdst] ----
        int ar = row0 + ln16; if (ar > N - 1) ar = N - 1;
        const u16* Ar2 = Tdst + (size_t)ar * 128 + quad * 8;
        f32x4 acc[2];
        #pragma unroll
        for (int t = 0; t < 2; ++t) acc[t] = (f32x4){bv[t], bv[t], bv[t], bv[t]};
        #pragma unroll
        for (int q = 0; q < 4; ++q){
            bf16x8 afl = *(const bf16x8*)&aggLDS[ln16 * 68 + q * 16 + quad * 4];
            bf16x8 afr = *(const bf16x8*)(Ar2 + q * 32);
            #pragma unroll
            for (int t = 0; t < 2; ++t){
                acc[t] = __builtin_amdgcn_mfma_f32_16x16x32_bf16(afl, BL[t][q], acc[t], 0, 0, 0);
                acc[t] = __builtin_amdgcn_mfma_f32_16x16x32_bf16(afr, BR[t][q], acc[t], 0, 0, 0);
            }
        }

        // ---- phase 3: row L2-norm across waves, scaled conv accumulate ----
        float ssr[4];
        #pragma unroll
        for (int r = 0; r < 4; ++r){
            float s = acc[0][r] * acc[0][r] + acc[1][r] * acc[1][r];
            #pragma unroll
            for (int m = 1; m < 16; m <<= 1) s += __shfl_xor(s, m);
            ssr[r] = s;
        }
        if (ln16 == 0){
            #pragma unroll
            for (int r = 0; r < 4; ++r) ssLDS[wave][quad * 4 + r] = ssr[r];
        }
        __syncthreads();
        #pragma unroll
        for (int r = 0; r < 4; ++r){
            int row = row0 + quad * 4 + r;
            if (row >= N) continue;
            int r16 = quad * 4 + r;
            float tot = ssLDS[0][r16] + ssLDS[1][r16] + ssLDS[2][r16] + ssLDS[3][r16];
            float s = scale / fmaxf(sqrtf(tot), 1e-12f);
            #pragma unroll
            for (int t = 0; t < 2; ++t){
                int col = wave * 32 + t * 16 + ln16;
                float* p = conv + (size_t)row * 128 + col;
                float v = acc[t][r] * s;
                if (beta) v += *p;
                *p = v;
            }
        }
        __syncthreads();   // protect aggLDS/ssLDS before next tile
    }
}

// ------ residual + LayerNorm, both node types in one launch (in-place f32) ------
__global__ __launch_bounds__(256) void ln2_kernel(
    const u16* __restrict__ TM, const u16* __restrict__ TH,
    const float* __restrict__ g_m, const float* __restrict__ be_m,
    const float* __restrict__ g_h, const float* __restrict__ be_h,
    float* __restrict__ out, int NM, int NH)
{
    int wid = (int)((blockIdx.x * (unsigned)blockDim.x + threadIdx.x) >> 6);
    int lane = threadIdx.x & 63;
    int ntot = NM + NH;
    if (wid >= ntot) return;
    const u16* T; const float *g, *be;
    if (wid < NM){ T = TM + (size_t)wid * 128; g = g_m; be = be_m; }
    else { T = TH + (size_t)(wid - NM) * 128; g = g_h; be = be_h; }
    u32 tu = *(const u32*)(T + lane * 2);
    float2* p = (float2*)(out + (size_t)wid * 128 + lane * 2);
    float2 cu = *p;
    float y0 = bf_lo(tu) + cu.x;
    float y1 = bf_hi(tu) + cu.y;
    float s1 = y0 + y1, s2 = y0 * y0 + y1 * y1;
    #pragma unroll
    for (int m = 1; m < 64; m <<= 1){ s1 += __shfl_xor(s1, m); s2 += __shfl_xor(s2, m); }
    float mean = s1 * (1.0f / 128.0f);
    float var = s2 * (1.0f / 128.0f) - mean * mean;
    float rstd = rsqrtf(var + 1e-5f);
    float2 gv = ((const float2*)g)[lane];
    float2 bv = ((const float2*)be)[lane];
    *p = make_float2((y0 - mean) * rstd * gv.x + bv.x,
                     (y1 - mean) * rstd * gv.y + bv.y);
}

extern "C" void kernel_launch(void* const* d_in, const int* in_sizes, int n_in,
                              void* d_out, int out_size, void* d_ws, size_t ws_size,
                              hipStream_t stream) {
    const float* xm    = (const float*)d_in[0];
    const float* xh    = (const float*)d_in[1];
    const float* Wnt_m = (const float*)d_in[2];  const float* bnt_m = (const float*)d_in[3];
    const float* Wnt_h = (const float*)d_in[4];  const float* bnt_h = (const float*)d_in[5];
    const float* Wl_mm = (const float*)d_in[6];  const float* bl_mm = (const float*)d_in[7];
    const float* Wr_mm = (const float*)d_in[8];
    const float* Wl_mh = (const float*)d_in[9];  const float* bl_mh = (const float*)d_in[10];
    const float* Wr_mh = (const float*)d_in[11];
    const float* Wl_hm = (const float*)d_in[12]; const float* bl_hm = (const float*)d_in[13];
    const float* Wr_hm = (const float*)d_in[14];
    const float* g_m   = (const float*)d_in[15]; const float* be_m  = (const float*)d_in[16];
    const float* g_h   = (const float*)d_in[17]; const float* be_h  = (const float*)d_in[18];
    const int* ei_mm = (const int*)d_in[19];
    const int* ei_mh = (const int*)d_in[20];
    const int* ei_hm = (const int*)d_in[21];

    const int D = 128;
    const int NM = in_sizes[0] / D;
    const int NH = in_sizes[1] / D;
    const int E1 = in_sizes[19] / 2;   // mm
    const int E2 = in_sizes[20] / 2;   // mh
    const int E3 = in_sizes[21] / 2;   // hm
    const int Esum = E1 + E2 + E3;
    const int n3 = 2 * NM + NH;        // type0: mm->M, type1: hm->M, type2: mh->H

    char* ws = (char*)d_ws;
    size_t woff = 0;
    auto alloc = [&](size_t bytes) -> void* {
        void* p = ws + woff;
        woff += (bytes + 255) & ~(size_t)255;
        return p;
    };
    u16* T_M   = (u16*)alloc((size_t)NM * D * 2);
    u16* T_H   = (u16*)alloc((size_t)NH * D * 2);
    int* CNT3  = (int*)alloc((size_t)n3 * 4);
    int* OFF3  = (int*)alloc((size_t)(n3 + 1) * 4);
    int* CUR3  = (int*)alloc((size_t)n3 * 4);
    int* SLOT3 = (int*)alloc((size_t)Esum * 4);
    int* PART  = (int*)alloc(1024 * 4);
    if (woff > ws_size) return;

    float* out    = (float*)d_out;
    float* CONV_M = out;
    float* CONV_H = out + (size_t)NM * D;

    const int b0 = 0, b1 = NM, b2 = 2 * NM;
    const int h0 = (E1 + 255) / 256, h1 = (E3 + 255) / 256, h2 = (E2 + 255) / 256;
    const int gm = 1024, gh = 1024;
    int Emax = E1 > E2 ? E1 : E2; if (E3 > Emax) Emax = E3;
    const dim3 egrid((Emax + 255) / 256, 3);
    const int scanBlocks = (n3 + 2047) / 2048;

    hipMemsetAsync(CNT3, 0, (size_t)n3 * 4, stream);

    // hist3 || ntgemm_M || ntgemm_H
    fusedA_kernel<<<h0 + h1 + h2 + gm + gh, 256, 0, stream>>>(
        ei_mm + E1, ei_hm + E3, ei_mh + E2,
        E1, E3, E2, b0, b1, b2, NM, NM, NH, CNT3, h0, h1, h2,
        xm, Wnt_m, bnt_m, T_M, NM,
        xh, Wnt_h, bnt_h, T_H, NH, gm, gh);

    scan_blocks_kernel<<<scanBlocks, 256, 0, stream>>>(CNT3, n3, OFF3, PART);
    scan_part_kernel<<<1, 128, 0, stream>>>(PART, scanBlocks, OFF3 + n3);
    scan_add_kernel<<<(n3 + 255) / 256, 256, 0, stream>>>(OFF3, CUR3, PART, n3);
    fill3_kernel<<<egrid, 256, 0, stream>>>(
        ei_mm, ei_hm, ei_mh,
        ei_mm + E1, ei_hm + E3, ei_mh + E2,
        E1, E3, E2, b0, b1, b2, NM, NM, NH, CUR3, SLOT3);

    // fused gather+SAGE per edge type
    sage_g_kernel<<<(NM + 15) / 16, 256, 0, stream>>>(
        T_M, T_M, OFF3 + b0, SLOT3, NM, Wl_mm, bl_mm, Wr_mm, CONV_M, NM, 0.5f, 0);
    sage_g_kernel<<<(NM + 15) / 16, 256, 0, stream>>>(
        T_H, T_M, OFF3 + b1, SLOT3, NH, Wl_hm, bl_hm, Wr_hm, CONV_M, NM, 0.5f, 1);
    sage_g_kernel<<<(NH + 15) / 16, 256, 0, stream>>>(
        T_M, T_H, OFF3 + b2, SLOT3, NM, Wl_mh, bl_mh, Wr_mh, CONV_H, NH, 1.0f, 0);

    // residual + LayerNorm (both types, in place on f32 d_out)
    ln2_kernel<<<(NM + NH + 3) / 4, 256, 0, stream>>>(
        T_M, T_H, g_m, be_m, g_h, be_h, out, NM, NH);
}

// Round 8
// 633.693 us; speedup vs baseline: 2.5336x; 1.0551x over previous
//
#include <hip/hip_runtime.h>

typedef unsigned short u16;
typedef unsigned int u32;
typedef __attribute__((ext_vector_type(8))) short bf16x8;
typedef __attribute__((ext_vector_type(4))) float f32x4;

__device__ __forceinline__ float bf_lo(u32 u){ return __uint_as_float(u << 16); }
__device__ __forceinline__ float bf_hi(u32 u){ return __uint_as_float(u & 0xffff0000u); }
__device__ __forceinline__ u16 f2bf(float f){
    u32 u = __float_as_uint(f);
    u32 r = (u + 0x7fffu + ((u >> 16) & 1u)) >> 16;
    return (u16)r;
}
__device__ __forceinline__ u32 pack2(float a, float b){
    return (u32)f2bf(a) | ((u32)f2bf(b) << 16);
}

// ======== fused: hist3 (atomic histogram) || ntgemm_M || ntgemm_H ========
__global__ __launch_bounds__(256) void fusedA_kernel(
    const int* __restrict__ d0, const int* __restrict__ d1, const int* __restrict__ d2,
    int E0, int E1, int E2, int b0, int b1, int b2, int n0, int n1, int n2,
    int* __restrict__ cnt, int h0, int h1, int h2,
    const float* __restrict__ Xm, const float* __restrict__ Wm,
    const float* __restrict__ bm, u16* __restrict__ Tm, int NM,
    const float* __restrict__ Xh, const float* __restrict__ Wh,
    const float* __restrict__ bh, u16* __restrict__ Th, int NH,
    int gm, int gh)
{
    int bid = blockIdx.x;
    int HB = h0 + h1 + h2;
    if (bid < HB){
        int t, lb;
        if (bid < h0){ t = 0; lb = bid; }
        else if (bid < h0 + h1){ t = 1; lb = bid - h0; }
        else { t = 2; lb = bid - h0 - h1; }
        const int* d = t == 0 ? d0 : (t == 1 ? d1 : d2);
        int E = t == 0 ? E0 : (t == 1 ? E1 : E2);
        int b = t == 0 ? b0 : (t == 1 ? b1 : b2);
        int n = t == 0 ? n0 : (t == 1 ? n1 : n2);
        int i = lb * 256 + threadIdx.x;
        if (i < E){
            int x = d[i];
            if ((unsigned)x < (unsigned)n) atomicAdd(&cnt[b + x], 1);
        }
        return;
    }
    bid -= HB;
    const float *A, *W, *bias; u16* C; int N, lgrid, lbid;
    if (bid < gm){ A = Xm; W = Wm; bias = bm; C = Tm; N = NM; lgrid = gm; lbid = bid; }
    else         { A = Xh; W = Wh; bias = bh; C = Th; N = NH; lgrid = gh; lbid = bid - gm; }

    int tid = threadIdx.x;
    int wave = tid >> 6, lane = tid & 63;
    int colHalf = wave & 1;
    int ln16 = lane & 15, quad = lane >> 4;

    bf16x8 Bfrag[4][4];
    #pragma unroll
    for (int t = 0; t < 4; ++t){
        int col = colHalf * 64 + t * 16 + ln16;
        #pragma unroll
        for (int q = 0; q < 4; ++q){
            bf16x8 f;
            #pragma unroll
            for (int j = 0; j < 8; ++j)
                f[j] = (short)f2bf(W[(q * 32 + quad * 8 + j) * 128 + col]);
            Bfrag[t][q] = f;
        }
    }
    float bv[4];
    #pragma unroll
    for (int t = 0; t < 4; ++t)
        bv[t] = bias[colHalf * 64 + t * 16 + ln16];

    int rowBlocks = (N + 15) >> 4;
    for (int rb = lbid * 2 + (wave >> 1); rb < rowBlocks; rb += lgrid * 2){
        int row0 = rb * 16;
        int ar = row0 + ln16; if (ar > N - 1) ar = N - 1;
        const float* Arow = A + (size_t)ar * 128 + quad * 8;
        bf16x8 Af[4];
        #pragma unroll
        for (int q = 0; q < 4; ++q){
            f32x4 lo = *(const f32x4*)(Arow + q * 32);
            f32x4 hi = *(const f32x4*)(Arow + q * 32 + 4);
            bf16x8 f;
            #pragma unroll
            for (int j = 0; j < 4; ++j){ f[j] = (short)f2bf(lo[j]); f[4+j] = (short)f2bf(hi[j]); }
            Af[q] = f;
        }
        f32x4 acc[4];
        #pragma unroll
        for (int t = 0; t < 4; ++t) acc[t] = (f32x4){bv[t], bv[t], bv[t], bv[t]};
        #pragma unroll
        for (int q = 0; q < 4; ++q)
            #pragma unroll
            for (int t = 0; t < 4; ++t)
                acc[t] = __builtin_amdgcn_mfma_f32_16x16x32_bf16(Af[q], Bfrag[t][q], acc[t], 0, 0, 0);
        #pragma unroll
        for (int t = 0; t < 4; ++t){
            int col = colHalf * 64 + t * 16 + ln16;
            #pragma unroll
            for (int r = 0; r < 4; ++r){
                int row = row0 + quad * 4 + r;
                if (row < N) C[(size_t)row * 128 + col] = f2bf(acc[t][r]);
            }
        }
    }
}

// ---------------- 3-phase device-wide exclusive scan ----------------
__global__ __launch_bounds__(256) void scan_blocks_kernel(
    const int* __restrict__ cnt, int n, int* __restrict__ off, int* __restrict__ part)
{
    __shared__ int lds[256];
    int tid = threadIdx.x;
    int base = blockIdx.x * 2048 + tid * 8;
    int v[8]; int s = 0;
    #pragma unroll
    for (int j = 0; j < 8; ++j){
        int idx = base + j;
        int c = (idx < n) ? cnt[idx] : 0;
        v[j] = s; s += c;
    }
    lds[tid] = s;
    __syncthreads();
    for (int d = 1; d < 256; d <<= 1){
        int t = (tid >= d) ? lds[tid - d] : 0;
        __syncthreads();
        lds[tid] += t;
        __syncthreads();
    }
    int thrBase = (tid > 0) ? lds[tid - 1] : 0;
    if (tid == 255) part[blockIdx.x] = lds[255];
    #pragma unroll
    for (int j = 0; j < 8; ++j){
        int idx = base + j;
        if (idx < n) off[idx] = thrBase + v[j];
    }
}

__global__ __launch_bounds__(128) void scan_part_kernel(
    int* __restrict__ part, int np, int* __restrict__ total_slot)
{
    __shared__ int lds[128];
    int tid = threadIdx.x;
    lds[tid] = (tid < np) ? part[tid] : 0;
    __syncthreads();
    for (int d = 1; d < 128; d <<= 1){
        int t = (tid >= d) ? lds[tid - d] : 0;
        __syncthreads();
        lds[tid] += t;
        __syncthreads();
    }
    if (tid < np) part[tid] = (tid > 0) ? lds[tid - 1] : 0;
    if (tid == 0) *total_slot = lds[np - 1 < 0 ? 0 : np - 1];
}

__global__ __launch_bounds__(256) void scan_add_kernel(
    int* __restrict__ off, int* __restrict__ cur, const int* __restrict__ part, int n)
{
    int i = blockIdx.x * 256 + threadIdx.x;
    if (i < n){
        int v = off[i] + part[i >> 11];
        off[i] = v;
        cur[i] = v;
    }
}

__global__ __launch_bounds__(256) void fill3_kernel(
    const int* __restrict__ s0, const int* __restrict__ s1, const int* __restrict__ s2,
    const int* __restrict__ d0, const int* __restrict__ d1, const int* __restrict__ d2,
    int E0, int E1, int E2, int b0, int b1, int b2, int n0, int n1, int n2,
    int* __restrict__ cur, int* __restrict__ slot)
{
    int t = blockIdx.y;
    int i = blockIdx.x * 256 + threadIdx.x;
    const int* sp = t == 0 ? s0 : (t == 1 ? s1 : s2);
    const int* dp = t == 0 ? d0 : (t == 1 ? d1 : d2);
    int E = t == 0 ? E0 : (t == 1 ? E1 : E2);
    int b = t == 0 ? b0 : (t == 1 ? b1 : b2);
    int n = t == 0 ? n0 : (t == 1 ? n1 : n2);
    if (i < E){
        int x = dp[i];
        if ((unsigned)x < (unsigned)n){
            int p = atomicAdd(&cur[b + x], 1);
            slot[p] = sp[i];
        }
    }
}

// ===== fused gather + SAGE with lane-parallel slot prefetch =====
// 4 waves/block; 16 dst rows per tile. Wave w gathers rows 4w..4w+3: one
// coalesced load gives the wave up to 64 neighbor indices per row (lane j
// holds slot[b+j]); indices broadcast via __shfl; neighbor-row loads are then
// fully independent (no dependent slot loads in the hot loop).
__global__ __launch_bounds__(256) void sage_g_kernel(
    const u16* __restrict__ Tsrc, const u16* __restrict__ Tdst,
    const int* __restrict__ off, const int* __restrict__ slot, int n_src,
    const float* __restrict__ Wl, const float* __restrict__ bl,
    const float* __restrict__ Wr, float* __restrict__ conv,
    int N, float scale, int beta)
{
    __shared__ u32 aggLDS[16 * 68];
    __shared__ float ssLDS[4][16];
    int tid = threadIdx.x;
    int wave = tid >> 6, lane = tid & 63;
    int ln16 = lane & 15, quad = lane >> 4;

    bf16x8 BL[2][4], BR[2][4];
    #pragma unroll
    for (int t = 0; t < 2; ++t){
        int col = wave * 32 + t * 16 + ln16;
        #pragma unroll
        for (int q = 0; q < 4; ++q){
            bf16x8 fl, fr;
            #pragma unroll
            for (int j = 0; j < 8; ++j){
                int k = q * 32 + quad * 8 + j;
                fl[j] = (short)f2bf(Wl[k * 128 + col]);
                fr[j] = (short)f2bf(Wr[k * 128 + col]);
            }
            BL[t][q] = fl; BR[t][q] = fr;
        }
    }
    float bv[2];
    #pragma unroll
    for (int t = 0; t < 2; ++t) bv[t] = bl[wave * 32 + t * 16 + ln16];

    int tiles = (N + 15) >> 4;
    for (int tile = blockIdx.x; tile < tiles; tile += gridDim.x){
        int row0 = tile * 16;

        // ---- phase 1a: prefetch neighbor indices for all 4 rows of this wave
        int rb[4], rdeg[4], rtake[4], myslot[4];
        #pragma unroll
        for (int r = 0; r < 4; ++r){
            int g = row0 + wave * 4 + r;
            int b = 0, e = 0;
            if (g < N){ b = off[g]; e = off[g + 1]; }
            rb[r] = b;
            int deg = e - b;
            rdeg[r] = deg;
            int take = deg < 64 ? deg : 64;
            rtake[r] = take;
            int s = 0;
            if (lane < take){
                s = slot[b + lane];
                if ((unsigned)s >= (unsigned)n_src) s = 0;
            }
            myslot[r] = s;
        }

        // ---- phase 1b: accumulate (addresses known upfront -> deep MLP) ----
        #pragma unroll
        for (int r = 0; r < 4; ++r){
            int lrow = wave * 4 + r;
            float p0 = 0.f, p1 = 0.f, q0 = 0.f, q1 = 0.f;
            float r0 = 0.f, r1 = 0.f, s0 = 0.f, s1 = 0.f;
            int take = rtake[r];
            int j = 0;
            for (; j + 4 <= take; j += 4){
                int i0 = __shfl(myslot[r], j);
                int i1 = __shfl(myslot[r], j + 1);
                int i2 = __shfl(myslot[r], j + 2);
                int i3 = __shfl(myslot[r], j + 3);
                u32 u0 = *(const u32*)(Tsrc + (size_t)i0 * 128 + lane * 2);
                u32 u1 = *(const u32*)(Tsrc + (size_t)i1 * 128 + lane * 2);
                u32 u2 = *(const u32*)(Tsrc + (size_t)i2 * 128 + lane * 2);
                u32 u3 = *(const u32*)(Tsrc + (size_t)i3 * 128 + lane * 2);
                p0 += bf_lo(u0); p1 += bf_hi(u0);
                q0 += bf_lo(u1); q1 += bf_hi(u1);
                r0 += bf_lo(u2); r1 += bf_hi(u2);
                s0 += bf_lo(u3); s1 += bf_hi(u3);
            }
            for (; j < take; ++j){
                int i0 = __shfl(myslot[r], j);
                u32 u0 = *(const u32*)(Tsrc + (size_t)i0 * 128 + lane * 2);
                p0 += bf_lo(u0); p1 += bf_hi(u0);
            }
            // rare tail: degree > 64
            for (int j2 = rb[r] + 64; j2 < rb[r] + rdeg[r]; ++j2){
                int i0 = slot[j2];
                if ((unsigned)i0 >= (unsigned)n_src) i0 = 0;
                u32 u0 = *(const u32*)(Tsrc + (size_t)i0 * 128 + lane * 2);
                p0 += bf_lo(u0); p1 += bf_hi(u0);
            }
            float a0 = (p0 + q0) + (r0 + s0);
            float a1 = (p1 + q1) + (r1 + s1);
            int c = rdeg[r] < 1 ? 1 : rdeg[r];
            float inv = 1.0f / (float)c;
            aggLDS[lrow * 68 + lane] = pack2(a0 * inv, a1 * inv);
        }
        __syncthreads();

        // ---- phase 2: two MFMA GEMM halves on [agg | Tdst] ----
        int ar = row0 + ln16; if (ar > N - 1) ar = N - 1;
        const u16* Ar2 = Tdst + (size_t)ar * 128 + quad * 8;
        f32x4 acc[2];
        #pragma unroll
        for (int t = 0; t < 2; ++t) acc[t] = (f32x4){bv[t], bv[t], bv[t], bv[t]};
        #pragma unroll
        for (int q = 0; q < 4; ++q){
            bf16x8 afl = *(const bf16x8*)&aggLDS[ln16 * 68 + q * 16 + quad * 4];
            bf16x8 afr = *(const bf16x8*)(Ar2 + q * 32);
            #pragma unroll
            for (int t = 0; t < 2; ++t){
                acc[t] = __builtin_amdgcn_mfma_f32_16x16x32_bf16(afl, BL[t][q], acc[t], 0, 0, 0);
                acc[t] = __builtin_amdgcn_mfma_f32_16x16x32_bf16(afr, BR[t][q], acc[t], 0, 0, 0);
            }
        }

        // ---- phase 3: row L2-norm across waves, scaled conv accumulate ----
        float ssr[4];
        #pragma unroll
        for (int r = 0; r < 4; ++r){
            float s = acc[0][r] * acc[0][r] + acc[1][r] * acc[1][r];
            #pragma unroll
            for (int m = 1; m < 16; m <<= 1) s += __shfl_xor(s, m);
            ssr[r] = s;
        }
        if (ln16 == 0){
            #pragma unroll
            for (int r = 0; r < 4; ++r) ssLDS[wave][quad * 4 + r] = ssr[r];
        }
        __syncthreads();
        #pragma unroll
        for (int r = 0; r < 4; ++r){
            int row = row0 + quad * 4 + r;
            if (row >= N) continue;
            int r16 = quad * 4 + r;
            float tot = ssLDS[0][r16] + ssLDS[1][r16] + ssLDS[2][r16] + ssLDS[3][r16];
            float s = scale / fmaxf(sqrtf(tot), 1e-12f);
            #pragma unroll
            for (int t = 0; t < 2; ++t){
                int col = wave * 32 + t * 16 + ln16;
                float* p = conv + (size_t)row * 128 + col;
                float v = acc[t][r] * s;
                if (beta) v += *p;
                *p = v;
            }
        }
        __syncthreads();
    }
}

// ------ residual + LayerNorm, both node types in one launch (in-place f32) ------
__global__ __launch_bounds__(256) void ln2_kernel(
    const u16* __restrict__ TM, const u16* __restrict__ TH,
    const float* __restrict__ g_m, const float* __restrict__ be_m,
    const float* __restrict__ g_h, const float* __restrict__ be_h,
    float* __restrict__ out, int NM, int NH)
{
    int wid = (int)((blockIdx.x * (unsigned)blockDim.x + threadIdx.x) >> 6);
    int lane = threadIdx.x & 63;
    int ntot = NM + NH;
    if (wid >= ntot) return;
    const u16* T; const float *g, *be;
    if (wid < NM){ T = TM + (size_t)wid * 128; g = g_m; be = be_m; }
    else { T = TH + (size_t)(wid - NM) * 128; g = g_h; be = be_h; }
    u32 tu = *(const u32*)(T + lane * 2);
    float2* p = (float2*)(out + (size_t)wid * 128 + lane * 2);
    float2 cu = *p;
    float y0 = bf_lo(tu) + cu.x;
    float y1 = bf_hi(tu) + cu.y;
    float s1 = y0 + y1, s2 = y0 * y0 + y1 * y1;
    #pragma unroll
    for (int m = 1; m < 64; m <<= 1){ s1 += __shfl_xor(s1, m); s2 += __shfl_xor(s2, m); }
    float mean = s1 * (1.0f / 128.0f);
    float var = s2 * (1.0f / 128.0f) - mean * mean;
    float rstd = rsqrtf(var + 1e-5f);
    float2 gv = ((const float2*)g)[lane];
    float2 bv = ((const float2*)be)[lane];
    *p = make_float2((y0 - mean) * rstd * gv.x + bv.x,
                     (y1 - mean) * rstd * gv.y + bv.y);
}

extern "C" void kernel_launch(void* const* d_in, const int* in_sizes, int n_in,
                              void* d_out, int out_size, void* d_ws, size_t ws_size,
                              hipStream_t stream) {
    const float* xm    = (const float*)d_in[0];
    const float* xh    = (const float*)d_in[1];
    const float* Wnt_m = (const float*)d_in[2];  const float* bnt_m = (const float*)d_in[3];
    const float* Wnt_h = (const float*)d_in[4];  const float* bnt_h = (const float*)d_in[5];
    const float* Wl_mm = (const float*)d_in[6];  const float* bl_mm = (const float*)d_in[7];
    const float* Wr_mm = (const float*)d_in[8];
    const float* Wl_mh = (const float*)d_in[9];  const float* bl_mh = (const float*)d_in[10];
    const float* Wr_mh = (const float*)d_in[11];
    const float* Wl_hm = (const float*)d_in[12]; const float* bl_hm = (const float*)d_in[13];
    const float* Wr_hm = (const float*)d_in[14];
    const float* g_m   = (const float*)d_in[15]; const float* be_m  = (const float*)d_in[16];
    const float* g_h   = (const float*)d_in[17]; const float* be_h  = (const float*)d_in[18];
    const int* ei_mm = (const int*)d_in[19];
    const int* ei_mh = (const int*)d_in[20];
    const int* ei_hm = (const int*)d_in[21];

    const int D = 128;
    const int NM = in_sizes[0] / D;
    const int NH = in_sizes[1] / D;
    const int E1 = in_sizes[19] / 2;   // mm
    const int E2 = in_sizes[20] / 2;   // mh
    const int E3 = in_sizes[21] / 2;   // hm
    const int Esum = E1 + E2 + E3;
    const int n3 = 2 * NM + NH;        // type0: mm->M, type1: hm->M, type2: mh->H

    char* ws = (char*)d_ws;
    size_t woff = 0;
    auto alloc = [&](size_t bytes) -> void* {
        void* p = ws + woff;
        woff += (bytes + 255) & ~(size_t)255;
        return p;
    };
    u16* T_M   = (u16*)alloc((size_t)NM * D * 2);
    u16* T_H   = (u16*)alloc((size_t)NH * D * 2);
    int* CNT3  = (int*)alloc((size_t)n3 * 4);
    int* OFF3  = (int*)alloc((size_t)(n3 + 1) * 4);
    int* CUR3  = (int*)alloc((size_t)n3 * 4);
    int* SLOT3 = (int*)alloc((size_t)Esum * 4);
    int* PART  = (int*)alloc(1024 * 4);
    if (woff > ws_size) return;

    float* out    = (float*)d_out;
    float* CONV_M = out;
    float* CONV_H = out + (size_t)NM * D;

    const int b0 = 0, b1 = NM, b2 = 2 * NM;
    const int h0 = (E1 + 255) / 256, h1 = (E3 + 255) / 256, h2 = (E2 + 255) / 256;
    const int gm = 1024, gh = 1024;
    int Emax = E1 > E2 ? E1 : E2; if (E3 > Emax) Emax = E3;
    const dim3 egrid((Emax + 255) / 256, 3);
    const int scanBlocks = (n3 + 2047) / 2048;

    hipMemsetAsync(CNT3, 0, (size_t)n3 * 4, stream);

    fusedA_kernel<<<h0 + h1 + h2 + gm + gh, 256, 0, stream>>>(
        ei_mm + E1, ei_hm + E3, ei_mh + E2,
        E1, E3, E2, b0, b1, b2, NM, NM, NH, CNT3, h0, h1, h2,
        xm, Wnt_m, bnt_m, T_M, NM,
        xh, Wnt_h, bnt_h, T_H, NH, gm, gh);

    scan_blocks_kernel<<<scanBlocks, 256, 0, stream>>>(CNT3, n3, OFF3, PART);
    scan_part_kernel<<<1, 128, 0, stream>>>(PART, scanBlocks, OFF3 + n3);
    scan_add_kernel<<<(n3 + 255) / 256, 256, 0, stream>>>(OFF3, CUR3, PART, n3);
    fill3_kernel<<<egrid, 256, 0, stream>>>(
        ei_mm, ei_hm, ei_mh,
        ei_mm + E1, ei_hm + E3, ei_mh + E2,
        E1, E3, E2, b0, b1, b2, NM, NM, NH, CUR3, SLOT3);

    sage_g_kernel<<<(NM + 15) / 16, 256, 0, stream>>>(
        T_M, T_M, OFF3 + b0, SLOT3, NM, Wl_mm, bl_mm, Wr_mm, CONV_M, NM, 0.5f, 0);
    sage_g_kernel<<<(NM + 15) / 16, 256, 0, stream>>>(
        T_H, T_M, OFF3 + b1, SLOT3, NH, Wl_hm, bl_hm, Wr_hm, CONV_M, NM, 0.5f, 1);
    sage_g_kernel<<<(NH + 15) / 16, 256, 0, stream>>>(
        T_M, T_H, OFF3 + b2, SLOT3, NM, Wl_mh, bl_mh, Wr_mh, CONV_H, NH, 1.0f, 0);

    ln2_kernel<<<(NM + NH + 3) / 4, 256, 0, stream>>>(
        T_M, T_H, g_m, be_m, g_h, be_h, out, NM, NH);
}